// Round 3
// baseline (21593.471 us; speedup 1.0000x reference)
//
#include <hip/hip_runtime.h>
#include <hip/hip_bf16.h>
#include <hip/hip_cooperative_groups.h>

namespace cg = cooperative_groups;

#define B_   256
#define T_   64
#define OBS_ 1024
#define ACT_ 6
#define STO_ 32
#define HID_ 1024
#define DET_ 1024
#define NTHREADS 131072   // 256 blocks * 512 threads
#define WLDS_BYTES 131072
#define SH_FLOATS 704

using bf16 = __bf16;
typedef __attribute__((ext_vector_type(8))) __bf16 bf16x8;
typedef __attribute__((ext_vector_type(4))) float f32x4;

struct Params {
  const float *obs, *actions, *eps_post;
  const float *in_w1, *in_b1, *in_w2, *in_b2;
  const float *gru_wih, *gru_whh, *gru_bih, *gru_bhh;
  const float *pr_w1, *pr_b1, *pr_w2, *pr_b2, *pr_mw, *pr_mb, *pr_sw, *pr_sb;
  const float *po_w1, *po_b1, *po_w2, *po_b2, *po_mw, *po_mb, *po_sw, *po_sb;
  float *feat, *pm, *ps, *qm, *qs;
  bf16 *w_phb, *w_qhb;
  bf16 *x1b, *x2b, *hb, *p1b, *q1b, *p2b, *q2b, *obsb;
  float *hf, *gi, *gh;
};

__device__ __forceinline__ f32x4 MF(bf16x8 a, bf16x8 b, f32x4 c) {
  return __builtin_amdgcn_mfma_f32_16x16x32_bf16(a, b, c, 0, 0, 0);
}

// GEMM on one CU: out[m0cu + 0..64*MT) x slice(64 or 32 n-cols), W resident in LDS.
// Wave wv: m-group (wv&3)*MT*16, n-half (wv>>2)*NF*16.
// W LDS layout: row-major rows of ROWB bytes, 16B chunk kc stored at ((kc ^ (row&7))<<4).
template<int MT, int NF, int SEG2, int RELU, int OUTF32>
__device__ __forceinline__ void gemm_cu(
    const bf16* __restrict__ A1, const bf16* __restrict__ A2,
    const char* __restrict__ wlds,
    const float* __restrict__ bias,   // pre-offset to slice n0 (or nullptr)
    void* __restrict__ outp,          // pre-offset to slice n0
    int ldo, int m0cu) {
  constexpr int ROWB = SEG2 ? 4096 : 2048;   // K=2048 (po1) or K=1024
  const int tid = threadIdx.x, lane = tid & 63;
  const int wv = tid >> 6, l15 = lane & 15, kg = lane >> 4;
  const int m0 = m0cu + (wv & 3) * (MT * 16);
  const int nloc = (wv >> 2) * (NF * 16);
  const int s = l15 & 7;

  f32x4 acc[MT][NF];
  #pragma unroll
  for (int a = 0; a < MT; ++a)
    #pragma unroll
    for (int b = 0; b < NF; ++b) acc[a][b] = f32x4{0.f, 0.f, 0.f, 0.f};

  const char* wrow[NF];
  #pragma unroll
  for (int nf = 0; nf < NF; ++nf)
    wrow[nf] = wlds + (nloc + nf * 16 + l15) * ROWB;

  const bf16* ar[MT];
  #pragma unroll
  for (int mt = 0; mt < MT; ++mt)
    ar[mt] = A1 + (size_t)(m0 + mt * 16 + l15) * 1024 + kg * 8;

  #pragma unroll 4
  for (int k0 = 0; k0 < 1024; k0 += 32) {
    bf16x8 af[MT], wf[NF];
    #pragma unroll
    for (int mt = 0; mt < MT; ++mt) af[mt] = *(const bf16x8*)(ar[mt] + k0);
    const int kcb = k0 >> 3;
    #pragma unroll
    for (int nf = 0; nf < NF; ++nf)
      wf[nf] = *(const bf16x8*)(wrow[nf] + (((kcb + kg) ^ s) << 4));
    #pragma unroll
    for (int mt = 0; mt < MT; ++mt)
      #pragma unroll
      for (int nf = 0; nf < NF; ++nf)
        acc[mt][nf] = MF(af[mt], wf[nf], acc[mt][nf]);
  }
  if (SEG2) {   // second K-segment (po1: obs part), chunks continue at kc=128
    #pragma unroll
    for (int mt = 0; mt < MT; ++mt)
      ar[mt] = A2 + (size_t)(m0 + mt * 16 + l15) * 1024 + kg * 8;
    #pragma unroll 4
    for (int k0 = 0; k0 < 1024; k0 += 32) {
      bf16x8 af[MT], wf[NF];
      #pragma unroll
      for (int mt = 0; mt < MT; ++mt) af[mt] = *(const bf16x8*)(ar[mt] + k0);
      const int kcb = 128 + (k0 >> 3);
      #pragma unroll
      for (int nf = 0; nf < NF; ++nf)
        wf[nf] = *(const bf16x8*)(wrow[nf] + (((kcb + kg) ^ s) << 4));
      #pragma unroll
      for (int mt = 0; mt < MT; ++mt)
        #pragma unroll
        for (int nf = 0; nf < NF; ++nf)
          acc[mt][nf] = MF(af[mt], wf[nf], acc[mt][nf]);
    }
  }

  // D layout: lane l, reg r -> row m0+mt*16+(l>>4)*4+r, col nloc+nf*16+(l&15)
  #pragma unroll
  for (int mt = 0; mt < MT; ++mt) {
    #pragma unroll
    for (int nf = 0; nf < NF; ++nf) {
      const int ncol = nloc + nf * 16 + l15;
      const float bv = bias ? bias[ncol] : 0.f;
      #pragma unroll
      for (int r = 0; r < 4; ++r) {
        float v = acc[mt][nf][r] + bv;
        if (RELU) v = fmaxf(v, 0.f);
        const size_t off = (size_t)(m0 + mt * 16 + kg * 4 + r) * ldo + ncol;
        if (OUTF32) ((float*)outp)[off] = v;
        else        ((bf16*)outp)[off] = (bf16)v;
      }
    }
  }
}

__global__ __launch_bounds__(512, 1) void rssm_kern(Params P) {
  cg::grid_group grid = cg::this_grid();
  extern __shared__ char dynsm[];
  char* wlds = dynsm;
  float* sh = (float*)(dynsm + WLDS_BYTES);
  const int tid = threadIdx.x;
  const int bid = blockIdx.x;
  const int gt  = bid * 512 + tid;

  // ---- role decode (fixed CU ownership) ----
  // [0,32) in2 x2 m-split | [32,128) wih x2 | [128,176) whh | [176,192) pr1
  // [192,224) po1 (32-row slices, K=2048) | [224,240) pr2 | [240,256) po2
  int role, slice, mh = 0;
  if (bid < 32)       { role = 0; slice = bid >> 1;        mh = bid & 1; }
  else if (bid < 128) { role = 1; slice = (bid - 32) >> 1; mh = (bid - 32) & 1; }
  else if (bid < 176) { role = 2; slice = bid - 128; }
  else if (bid < 192) { role = 3; slice = bid - 176; }
  else if (bid < 224) { role = 4; slice = bid - 192; }
  else if (bid < 240) { role = 5; slice = bid - 224; }
  else                { role = 6; slice = bid - 240; }

  // ---- stage 0: W slice -> LDS (bf16, swizzled); head weights -> bf16; state init ----
  {
    const float* src; int rows, K;
    switch (role) {
      case 0:  src = P.in_w2   + (size_t)slice * 64 * 1024; rows = 64; K = 1024; break;
      case 1:  src = P.gru_wih + (size_t)slice * 64 * 1024; rows = 64; K = 1024; break;
      case 2:  src = P.gru_whh + (size_t)slice * 64 * 1024; rows = 64; K = 1024; break;
      case 3:  src = P.pr_w1   + (size_t)slice * 64 * 1024; rows = 64; K = 1024; break;
      case 4:  src = P.po_w1   + (size_t)slice * 32 * 2048; rows = 32; K = 2048; break;
      case 5:  src = P.pr_w2   + (size_t)slice * 64 * 1024; rows = 64; K = 1024; break;
      default: src = P.po_w2   + (size_t)slice * 64 * 1024; rows = 64; K = 1024; break;
    }
    const int kcn = K >> 3, rowb = K * 2;
    for (int idx = tid; idx < rows * kcn; idx += 512) {
      const int row = idx / kcn, kc = idx - row * kcn;
      const float* sp = src + (size_t)row * K + kc * 8;
      bf16x8 v;
      #pragma unroll
      for (int j = 0; j < 8; ++j) v[j] = (bf16)sp[j];
      *(bf16x8*)(wlds + row * rowb + (((kc ^ (row & 7))) << 4)) = v;
    }
    for (int i = gt; i < STO_ * HID_; i += NTHREADS) {
      P.w_phb[i]               = (bf16)P.pr_mw[i];
      P.w_phb[STO_ * HID_ + i] = (bf16)P.pr_sw[i];
      P.w_qhb[i]               = (bf16)P.po_mw[i];
      P.w_qhb[STO_ * HID_ + i] = (bf16)P.po_sw[i];
    }
    for (int i = gt; i < B_ * HID_; i += NTHREADS) {
      P.x1b[i] = (bf16)fmaxf(P.in_b1[i & (HID_ - 1)], 0.f);   // z0=0, a0=0
      P.hb[i]  = (bf16)0.f;
      P.hf[i]  = 0.f;
    }
  }
  grid.sync();

  for (int t = 0; t < T_; ++t) {
    // ---- A: x2 = relu(x1@in2^T+b2) [in2 CUs] ; gh = h@whh^T+bhh [whh CUs] ----
    if (role == 0) {
      gemm_cu<2, 2, 0, 1, 0>(P.x1b, nullptr, wlds, P.in_b2 + slice * 64,
                             P.x2b + slice * 64, HID_, mh * 128);
    } else if (role == 2) {
      gemm_cu<4, 2, 0, 0, 1>(P.hb, nullptr, wlds, P.gru_bhh + slice * 64,
                             P.gh + slice * 64, 3 * DET_, 0);
    }
    grid.sync();

    // ---- B: gi = x2@wih^T+bih [wih CUs] ----
    if (role == 1) {
      gemm_cu<2, 2, 0, 0, 1>(P.x2b, nullptr, wlds, P.gru_bih + slice * 64,
                             P.gi + slice * 64, 3 * DET_, mh * 128);
    }
    grid.sync();

    // ---- C: GRU elementwise + feat h-part + obs->bf16 (all CUs) ----
    #pragma unroll
    for (int rep = 0; rep < 2; ++rep) {
      const int idx = gt + rep * NTHREADS;        // < 262144
      const int m = idx >> 10, i = idx & 1023;
      const size_t base = (size_t)m * 3072;
      float r  = P.gi[base + i]        + P.gh[base + i];
      float u  = P.gi[base + 1024 + i] + P.gh[base + 1024 + i];
      float nn = P.gi[base + 2048 + i];
      float hn = P.gh[base + 2048 + i];
      r = 1.f / (1.f + __expf(-r));
      u = 1.f / (1.f + __expf(-u));
      float n = tanhf(nn + r * hn);
      float h = P.hf[idx];
      float hnew = (1.f - u) * n + u * h;
      P.hf[idx] = hnew;
      P.hb[idx] = (bf16)hnew;
      P.feat[((size_t)m * T_ + t) * 1056 + i] = hnew;
      P.obsb[idx] = (bf16)P.obs[((size_t)m * T_ + t) * OBS_ + i];
    }
    grid.sync();

    // ---- D: pr1 [pr1 CUs] ; po1 (K=2048, two segs) [po1 CUs] ----
    if (role == 3) {
      gemm_cu<4, 2, 0, 1, 0>(P.hb, nullptr, wlds, P.pr_b1 + slice * 64,
                             P.p1b + slice * 64, HID_, 0);
    } else if (role == 4) {
      gemm_cu<4, 1, 1, 1, 0>(P.hb, P.obsb, wlds, P.po_b1 + slice * 32,
                             P.q1b + slice * 32, HID_, 0);
    }
    grid.sync();

    // ---- E: pr2 ; po2 ----
    if (role == 5) {
      gemm_cu<4, 2, 0, 1, 0>(P.p1b, nullptr, wlds, P.pr_b2 + slice * 64,
                             P.p2b + slice * 64, HID_, 0);
    } else if (role == 6) {
      gemm_cu<4, 2, 0, 1, 0>(P.q1b, nullptr, wlds, P.po_b2 + slice * 64,
                             P.q2b + slice * 64, HID_, 0);
    }
    grid.sync();

    // ---- F: heads + finish (VALU), block = batch row m ----
    {
      const int m = bid;
      const int o = tid >> 2, th = tid & 3;     // o in [0,128), th = K-quarter
      const bf16* srcv = ((o < 64) ? P.p2b : P.q2b) + (size_t)m * HID_ + th * 256;
      const bf16* wr   = ((o < 64) ? (P.w_phb + (size_t)o * HID_)
                                   : (P.w_qhb + (size_t)(o - 64) * HID_)) + th * 256;
      float acc = 0.f;
      #pragma unroll 4
      for (int k = 0; k < 256; k += 8) {
        bf16x8 av  = *(const bf16x8*)(srcv + k);
        bf16x8 wv8 = *(const bf16x8*)(wr + k);
        #pragma unroll
        for (int jj = 0; jj < 8; ++jj) acc = fmaf((float)av[jj], (float)wv8[jj], acc);
      }
      sh[tid] = acc;                             // partial[o][th]
      if (tid < ACT_) sh[608 + tid] = P.actions[((size_t)m * T_ + t) * ACT_ + tid];
      __syncthreads();
      if (tid < 128) {
        const float v = sh[tid * 4] + sh[tid * 4 + 1] + sh[tid * 4 + 2] + sh[tid * 4 + 3];
        const size_t ob = ((size_t)m * T_ + t) * STO_;
        if (tid < 32) {
          P.pm[ob + tid] = v + P.pr_mb[tid];
        } else if (tid < 64) {
          float x = v + P.pr_sb[tid - 32];
          P.ps[ob + tid - 32] = __expf(fminf(fmaxf(x, -5.f), 2.f));
        } else if (tid < 96) {
          float x = v + P.po_mb[tid - 64];
          P.qm[ob + tid - 64] = x; sh[512 + tid - 64] = x;
        } else {
          float x = v + P.po_sb[tid - 96];
          x = __expf(fminf(fmaxf(x, -5.f), 2.f));
          P.qs[ob + tid - 96] = x; sh[544 + tid - 96] = x;
        }
      }
      __syncthreads();
      if (tid < STO_) {
        float z = sh[512 + tid] + sh[544 + tid] * P.eps_post[((size_t)m * T_ + t) * STO_ + tid];
        sh[576 + tid] = z;
        P.feat[((size_t)m * T_ + t) * 1056 + 1024 + tid] = z;
      }
      __syncthreads();
      // next-step x1 = relu([z,a]@in_w1^T + in_b1), K=38 fp32
      #pragma unroll
      for (int rep = 0; rep < 2; ++rep) {
        const int n = tid + rep * 512;
        const float* w = P.in_w1 + (size_t)n * 38;
        float a = P.in_b1[n];
        #pragma unroll
        for (int k = 0; k < STO_; ++k) a = fmaf(sh[576 + k], w[k], a);
        #pragma unroll
        for (int k = 0; k < ACT_; ++k) a = fmaf(sh[608 + k], w[32 + k], a);
        P.x1b[(size_t)m * HID_ + n] = (bf16)fmaxf(a, 0.f);
      }
    }
    grid.sync();
  }
}

extern "C" void kernel_launch(void* const* d_in, const int* in_sizes, int n_in,
                              void* d_out, int out_size, void* d_ws, size_t ws_size,
                              hipStream_t stream) {
  (void)in_sizes; (void)n_in; (void)out_size; (void)ws_size;
  Params P;
  P.obs      = (const float*)d_in[0];
  P.actions  = (const float*)d_in[1];
  P.eps_post = (const float*)d_in[3];   // eps_prior (d_in[2]) unused by the math
  P.in_w1 = (const float*)d_in[4];  P.in_b1 = (const float*)d_in[5];
  P.in_w2 = (const float*)d_in[6];  P.in_b2 = (const float*)d_in[7];
  P.gru_wih = (const float*)d_in[8];  P.gru_whh = (const float*)d_in[9];
  P.gru_bih = (const float*)d_in[10]; P.gru_bhh = (const float*)d_in[11];
  P.pr_w1 = (const float*)d_in[12]; P.pr_b1 = (const float*)d_in[13];
  P.pr_w2 = (const float*)d_in[14]; P.pr_b2 = (const float*)d_in[15];
  P.pr_mw = (const float*)d_in[16]; P.pr_mb = (const float*)d_in[17];
  P.pr_sw = (const float*)d_in[18]; P.pr_sb = (const float*)d_in[19];
  P.po_w1 = (const float*)d_in[20]; P.po_b1 = (const float*)d_in[21];
  P.po_w2 = (const float*)d_in[22]; P.po_b2 = (const float*)d_in[23];
  P.po_mw = (const float*)d_in[24]; P.po_mb = (const float*)d_in[25];
  P.po_sw = (const float*)d_in[26]; P.po_sb = (const float*)d_in[27];

  P.feat = (float*)d_out;
  P.pm = P.feat + (size_t)B_ * T_ * 1056;
  P.ps = P.pm + (size_t)B_ * T_ * STO_;
  P.qm = P.ps + (size_t)B_ * T_ * STO_;
  P.qs = P.qm + (size_t)B_ * T_ * STO_;

  char* wp_ = (char*)d_ws;
  auto carve = [&](size_t bytes) -> void* {
    void* r = (void*)wp_;
    wp_ += (bytes + 255) & ~(size_t)255;
    return r;
  };
  P.w_phb = (bf16*)carve((size_t)64 * HID_ * 2);
  P.w_qhb = (bf16*)carve((size_t)64 * HID_ * 2);
  P.x1b  = (bf16*)carve((size_t)B_ * HID_ * 2);
  P.x2b  = (bf16*)carve((size_t)B_ * HID_ * 2);
  P.hb   = (bf16*)carve((size_t)B_ * DET_ * 2);
  P.p1b  = (bf16*)carve((size_t)B_ * HID_ * 2);
  P.q1b  = (bf16*)carve((size_t)B_ * HID_ * 2);
  P.p2b  = (bf16*)carve((size_t)B_ * HID_ * 2);
  P.q2b  = (bf16*)carve((size_t)B_ * HID_ * 2);
  P.obsb = (bf16*)carve((size_t)B_ * OBS_ * 2);
  P.hf   = (float*)carve((size_t)B_ * DET_ * 4);
  P.gi   = (float*)carve((size_t)B_ * 3 * DET_ * 4);
  P.gh   = (float*)carve((size_t)B_ * 3 * DET_ * 4);

  void* kp[] = { (void*)&P };
  hipLaunchCooperativeKernel((const void*)rssm_kern, dim3(256), dim3(512), kp,
                             (unsigned)(WLDS_BYTES + SH_FLOATS * 4), stream);
}